// Round 1
// baseline (1197.751 us; speedup 1.0000x reference)
//
#include <hip/hip_runtime.h>

#define B_ 8
#define M_ 2048
#define D_ 1024
#define N_ 128
#define P_ 16
#define NP_ 2048
#define BM_ 16384

typedef __attribute__((ext_vector_type(8))) short bf16x8;
typedef __attribute__((ext_vector_type(4))) float f32x4;
typedef unsigned short ushort_t;

__device__ __forceinline__ ushort_t f2bf(float f) {
    union { float f; unsigned u; } v; v.f = f;
    unsigned r = v.u + 0x7fffu + ((v.u >> 16) & 1u);
    return (ushort_t)(r >> 16);
}

__device__ __forceinline__ void async_copy16(const void* g, void* l) {
    __builtin_amdgcn_global_load_lds((const __attribute__((address_space(1))) void*)g,
                                     (__attribute__((address_space(3))) void*)l, 16, 0, 0);
}

// ---------------------------------------------------------------------------
// Generic batched TN GEMM: C[i,j] = sum_k A[i,k]*B[j,k] (+bias[i])
// A: [I rows][K] row-stride lda (bf16), B: [J rows][K] row-stride ldb (bf16)
// C address = batch*c_bs + (i>>4)*ci_hi + (i&15)*ci_lo + (j>>4)*cj_hi + (j&15)*cj_lo
// Tile: 128x128, BK=64, 256 threads (4 waves 2x2), mfma 16x16x32 bf16.
// All dims assumed divisible (verified for every launch below).
// ---------------------------------------------------------------------------
template<int OUT_BF16, int HAS_BIAS>
__global__ __launch_bounds__(256, 2)
void gemm_tn(const ushort_t* __restrict__ A, const ushort_t* __restrict__ Bm,
             void* __restrict__ C, const float* __restrict__ bias,
             int K, int lda, int ldb,
             long a_bs, long b_bs, long c_bs, long bias_bs,
             long ci_hi, long ci_lo, long cj_hi, long cj_lo)
{
    __shared__ __align__(16) ushort_t As[128 * 64];
    __shared__ __align__(16) ushort_t Bs[128 * 64];

    const int t = threadIdx.x;
    const int lane = t & 63;
    const int w = t >> 6;
    const int wr = w >> 1, wc = w & 1;
    const int quad = lane >> 4, lr = lane & 15;
    const int i0 = blockIdx.y * 128;
    const int j0 = blockIdx.x * 128;
    const int batch = blockIdx.z;

    const ushort_t* Ab = A + (size_t)batch * a_bs;
    const ushort_t* Bb = Bm + (size_t)batch * b_bs;

    f32x4 acc[4][4];
#pragma unroll
    for (int a = 0; a < 4; ++a)
#pragma unroll
        for (int b = 0; b < 4; ++b)
            acc[a][b] = (f32x4){0.f, 0.f, 0.f, 0.f};

    for (int kt = 0; kt < K; kt += 64) {
        // ---- stage global -> LDS (width-16 async, XOR chunk swizzle) ----
#pragma unroll
        for (int c = 0; c < 4; ++c) {
            int idx = c * 256 + t;
            int row = idx >> 3, slot = idx & 7;
            int chunk = slot ^ (row & 7);          // logical k-chunk fetched into this slot
            const ushort_t* ga = Ab + (size_t)(i0 + row) * lda + kt + chunk * 8;
            const ushort_t* gb = Bb + (size_t)(j0 + row) * ldb + kt + chunk * 8;
            char* la = (char*)As + c * 4096 + w * 1024;   // wave-uniform base; HW adds lane*16
            char* lb = (char*)Bs + c * 4096 + w * 1024;
            async_copy16(ga, la);
            async_copy16(gb, lb);
        }
        __syncthreads();

#pragma unroll
        for (int ks = 0; ks < 2; ++ks) {
            bf16x8 af[4], bfr[4];
#pragma unroll
            for (int mt = 0; mt < 4; ++mt) {
                int row = wr * 64 + mt * 16 + lr;
                int chunk = ks * 4 + quad;
                int slot = chunk ^ (row & 7);
                af[mt] = *(const bf16x8*)((const char*)As + row * 128 + slot * 16);
            }
#pragma unroll
            for (int nt = 0; nt < 4; ++nt) {
                int col = wc * 64 + nt * 16 + lr;
                int chunk = ks * 4 + quad;
                int slot = chunk ^ (col & 7);
                bfr[nt] = *(const bf16x8*)((const char*)Bs + col * 128 + slot * 16);
            }
#pragma unroll
            for (int mt = 0; mt < 4; ++mt)
#pragma unroll
                for (int nt = 0; nt < 4; ++nt)
                    acc[mt][nt] = __builtin_amdgcn_mfma_f32_16x16x32_bf16(af[mt], bfr[nt], acc[mt][nt], 0, 0, 0);
        }
        __syncthreads();
    }

    // ---- epilogue: C/D layout col=lane&15, row=quad*4+reg ----
    long cbase = (long)batch * c_bs;
#pragma unroll
    for (int mt = 0; mt < 4; ++mt) {
#pragma unroll
        for (int nt = 0; nt < 4; ++nt) {
            int j = j0 + wc * 64 + nt * 16 + lr;
            long jpart = (long)(j >> 4) * cj_hi + (long)(j & 15) * cj_lo;
            f32x4 v = acc[mt][nt];
#pragma unroll
            for (int r = 0; r < 4; ++r) {
                int i = i0 + wr * 64 + mt * 16 + quad * 4 + r;
                float val = v[r];
                if (HAS_BIAS) val += bias[(size_t)batch * bias_bs + i];
                long addr = cbase + (long)(i >> 4) * ci_hi + (long)(i & 15) * ci_lo + jpart;
                if (OUT_BF16) ((ushort_t*)C)[addr] = f2bf(val);
                else          ((float*)C)[addr] = val;
            }
        }
    }
}

// ---------------------------------------------------------------------------
// Elementwise cast fp32 -> bf16 (4 elems/thread)
// ---------------------------------------------------------------------------
__global__ __launch_bounds__(256)
void cast_bf16(const float* __restrict__ in, ushort_t* __restrict__ out)
{
    size_t i = (size_t)blockIdx.x * 256 + threadIdx.x;
    float4 f = *(const float4*)(in + i * 4);
    union { ushort_t us[4]; uint2 v; } pk;
    pk.us[0] = f2bf(f.x); pk.us[1] = f2bf(f.y);
    pk.us[2] = f2bf(f.z); pk.us[3] = f2bf(f.w);
    *(uint2*)(out + i * 4) = pk.v;
}

// ---------------------------------------------------------------------------
// Tiled transpose + cast: in fp32 [R][C] (ldi) -> out bf16 [C][R] (ldo)
// grid (C/64, R/64, batch)
// ---------------------------------------------------------------------------
__global__ __launch_bounds__(256)
void transpose_cast(const float* __restrict__ in, ushort_t* __restrict__ out,
                    int ldi, int ldo, long in_bs, long out_bs)
{
    __shared__ float tile[64][65];
    int t = threadIdx.x;
    const float* ib = in + (size_t)blockIdx.z * in_bs;
    ushort_t* ob = out + (size_t)blockIdx.z * out_bs;
    int c0 = blockIdx.x * 64, r0 = blockIdx.y * 64;
#pragma unroll
    for (int it = 0; it < 16; ++it) {
        int r = it * 4 + (t >> 6);
        int c = t & 63;
        tile[r][c] = ib[(size_t)(r0 + r) * ldi + c0 + c];
    }
    __syncthreads();
#pragma unroll
    for (int it = 0; it < 8; ++it) {
        int rr = it * 8 + (t >> 5);        // output row (= c index)
        int cc = (t & 31) * 2;             // output col (= r index), pair
        ushort2 pk;
        pk.x = f2bf(tile[cc][rr]);
        pk.y = f2bf(tile[cc + 1][rr]);
        *(ushort2*)(ob + (size_t)(c0 + rr) * ldo + r0 + cc) = pk;
    }
}

// ---------------------------------------------------------------------------
// Dispatch softmax: softmax over b (8 vals) of L[b][m][np] fp32,
// write transposed dT[b][np][m] bf16.  Tile 32(m) x 64(np); grid (NP/64, M/32).
// ---------------------------------------------------------------------------
__global__ __launch_bounds__(256)
void softmax_b(const float* __restrict__ L, ushort_t* __restrict__ dT)
{
    int t = threadIdx.x;
    int n0 = blockIdx.x * 64, m0 = blockIdx.y * 32;
    int ncol = t & 63, mb = t >> 6;

    float vals[8][8];   // [b][it]
#pragma unroll
    for (int b = 0; b < 8; ++b)
#pragma unroll
        for (int it = 0; it < 8; ++it) {
            int m = m0 + it * 4 + mb;
            vals[b][it] = L[(size_t)b * (M_ * (size_t)NP_) + (size_t)m * NP_ + n0 + ncol];
        }

    float inv[8];
#pragma unroll
    for (int it = 0; it < 8; ++it) {
        float mx = vals[0][it];
#pragma unroll
        for (int b = 1; b < 8; ++b) mx = fmaxf(mx, vals[b][it]);
        float s = 0.f;
#pragma unroll
        for (int b = 0; b < 8; ++b) { vals[b][it] = __expf(vals[b][it] - mx); s += vals[b][it]; }
        inv[it] = 1.f / s;
    }

    __shared__ float tile[64][33];
#pragma unroll
    for (int b = 0; b < 8; ++b) {
        __syncthreads();
#pragma unroll
        for (int it = 0; it < 8; ++it)
            tile[ncol][it * 4 + mb] = vals[b][it] * inv[it];
        __syncthreads();
#pragma unroll
        for (int it2 = 0; it2 < 4; ++it2) {
            int rr = it2 * 16 + (t >> 4);
            int cc = (t & 15) * 2;
            ushort2 pk;
            pk.x = f2bf(tile[rr][cc]);
            pk.y = f2bf(tile[rr][cc + 1]);
            *(ushort2*)(dT + (size_t)b * (NP_ * (size_t)M_) + (size_t)(n0 + rr) * M_ + m0 + cc) = pk;
        }
    }
}

// ---------------------------------------------------------------------------
// Combine softmax: softmax over 2048 slots per (b,m) row of L; out bf16 same layout.
// One block per row; 256 threads x 8 elems.
// ---------------------------------------------------------------------------
__global__ __launch_bounds__(256)
void softmax_np(const float* __restrict__ L, ushort_t* __restrict__ Cb)
{
    int row = blockIdx.x;
    const float* Lr = L + (size_t)row * NP_;
    int t = threadIdx.x;
    int w = t >> 6, lane = t & 63;

    float v[8];
    float4 u0 = *(const float4*)(Lr + t * 8);
    float4 u1 = *(const float4*)(Lr + t * 8 + 4);
    v[0] = u0.x; v[1] = u0.y; v[2] = u0.z; v[3] = u0.w;
    v[4] = u1.x; v[5] = u1.y; v[6] = u1.z; v[7] = u1.w;

    float mx = v[0];
#pragma unroll
    for (int j = 1; j < 8; ++j) mx = fmaxf(mx, v[j]);
#pragma unroll
    for (int off = 32; off > 0; off >>= 1) mx = fmaxf(mx, __shfl_xor(mx, off));

    __shared__ float red[8];
    if (lane == 0) red[w] = mx;
    __syncthreads();
    mx = fmaxf(fmaxf(red[0], red[1]), fmaxf(red[2], red[3]));

    float s = 0.f;
#pragma unroll
    for (int j = 0; j < 8; ++j) { v[j] = __expf(v[j] - mx); s += v[j]; }
#pragma unroll
    for (int off = 32; off > 0; off >>= 1) s += __shfl_xor(s, off);
    if (lane == 0) red[4 + w] = s;
    __syncthreads();
    s = red[4] + red[5] + red[6] + red[7];
    float is = 1.f / s;

    union { ushort_t us[8]; int4 v4; } pk;
#pragma unroll
    for (int j = 0; j < 8; ++j) pk.us[j] = f2bf(v[j] * is);
    *(int4*)(Cb + (size_t)row * NP_ + t * 8) = pk.v4;
}

// ---------------------------------------------------------------------------
// Host launch
// ---------------------------------------------------------------------------
extern "C" void kernel_launch(void* const* d_in, const int* in_sizes, int n_in,
                              void* d_out, int out_size, void* d_ws, size_t ws_size,
                              hipStream_t stream)
{
    (void)in_sizes; (void)n_in; (void)out_size; (void)ws_size;
    const float* x     = (const float*)d_in[0];   // [B][M][D]
    const float* phi   = (const float*)d_in[1];   // [D][N*P]
    const float* w_exp = (const float*)d_in[2];   // [N][D][D]
    const float* b_exp = (const float*)d_in[3];   // [N][D]
    float* out = (float*)d_out;                   // [B][M][D]
    char* ws = (char*)d_ws;

    // workspace layout (bytes); wT aliases the region dead after stage C
    ushort_t* xbf   = (ushort_t*)(ws + 0);          // 33.5 MB  [BM][D] bf16
    ushort_t* xT    = (ushort_t*)(ws + 33554432);   // 33.5 MB  [b][D][M] bf16
    ushort_t* phiT  = (ushort_t*)(ws + 67108864);   // 4 MB     [NP][D] bf16
    float*    L     = (float*)   (ws + 71303168);   // 134 MB   [BM][NP] fp32
    ushort_t* dT    = (ushort_t*)(ws + 205520896);  // 67 MB    [b][NP][M] bf16
    ushort_t* wT    = (ushort_t*)(ws + 0);          // 268 MB   [n][e][d] bf16 (alias)
    ushort_t* cmb   = (ushort_t*)(ws + 272629760);  // 67 MB    [b][M][NP] bf16
    ushort_t* slots = (ushort_t*)(ws + 339738624);  // 33.5 MB  [n][b][p][d] bf16
    ushort_t* eoT   = (ushort_t*)(ws + 373293056);  // 33.5 MB  [b][e][np] bf16
    // total 406.8 MB

    // 1. x -> bf16 (row-major [bm][d])
    cast_bf16<<<dim3(BM_ * D_ / 1024), 256, 0, stream>>>(x, xbf);
    // 2. phi [D][NP] -> phiT [NP][D]
    transpose_cast<<<dim3(NP_ / 64, D_ / 64, 1), 256, 0, stream>>>(phi, phiT, NP_, D_, 0, 0);
    // 3. x [b][M][D] -> xT [b][D][M]
    transpose_cast<<<dim3(D_ / 64, M_ / 64, B_), 256, 0, stream>>>(x, xT, D_, M_,
        (long)M_ * D_, (long)D_ * M_);
    // 4. Stage A: L[bm][np] = sum_d xbf[bm][d] * phiT[np][d]    (fp32 out)
    gemm_tn<0, 0><<<dim3(NP_ / 128, BM_ / 128, 1), 256, 0, stream>>>(
        xbf, phiT, L, nullptr, D_, D_, D_,
        0, 0, 0, 0,
        16L * NP_, NP_, 16, 1);
    // 5. dispatch softmax (over b) -> dT [b][np][m] bf16
    softmax_b<<<dim3(NP_ / 64, M_ / 32), 256, 0, stream>>>(L, dT);
    // 6. combine softmax (over np) -> cmb [b][m][np] bf16
    softmax_np<<<dim3(B_ * M_), 256, 0, stream>>>(L, cmb);
    // 7. Stage C: slots[n][b][p][d] = sum_m dT[b][np][m] * xT[b][d][m]
    gemm_tn<1, 0><<<dim3(D_ / 128, NP_ / 128, B_), 256, 0, stream>>>(
        dT, xT, slots, nullptr, M_, M_, M_,
        (long)NP_ * M_, (long)D_ * M_, (long)P_ * D_, 0,
        (long)B_ * P_ * D_, D_, 16, 1);
    // 8. w_exp [n][d][e] -> wT [n][e][d] bf16 (aliases dead region)
    transpose_cast<<<dim3(D_ / 64, D_ / 64, N_), 256, 0, stream>>>(w_exp, wT, D_, D_,
        (long)D_ * D_, (long)D_ * D_);
    // 9. Stage D: eoT[b][e][np] = sum_d wT[n][e][d] * slots[n][(b,p)][d] + b_exp[n][e]
    gemm_tn<1, 1><<<dim3(1, D_ / 128, N_), 256, 0, stream>>>(
        wT, slots, eoT, b_exp, D_, D_, D_,
        (long)D_ * D_, (long)B_ * P_ * D_, 16, D_,
        16L * NP_, NP_, (long)D_ * NP_, 1);
    // 10. Stage E: out[b][m][d] = sum_np cmb[b][m][np] * eoT[b][d][np]   (fp32 out)
    gemm_tn<0, 0><<<dim3(D_ / 128, M_ / 128, B_), 256, 0, stream>>>(
        cmb, eoT, out, nullptr, NP_, NP_, NP_,
        (long)M_ * NP_, (long)D_ * NP_, (long)M_ * D_, 0,
        16L * D_, D_, 16, 1);
}

// Round 2
// 1066.237 us; speedup vs baseline: 1.1233x; 1.1233x over previous
//
#include <hip/hip_runtime.h>

#define B_ 8
#define M_ 2048
#define D_ 1024
#define N_ 128
#define P_ 16
#define NP_ 2048
#define BM_ 16384

typedef __attribute__((ext_vector_type(8))) short bf16x8;
typedef __attribute__((ext_vector_type(4))) float f32x4;
typedef unsigned short ushort_t;

__device__ __forceinline__ ushort_t f2bf(float f) {
    union { float f; unsigned u; } v; v.f = f;
    unsigned r = v.u + 0x7fffu + ((v.u >> 16) & 1u);
    return (ushort_t)(r >> 16);
}

__device__ __forceinline__ float bf2f(ushort_t u) {
    union { unsigned u; float f; } v; v.u = ((unsigned)u) << 16;
    return v.f;
}

__device__ __forceinline__ void async_copy16(const void* g, void* l) {
    __builtin_amdgcn_global_load_lds((const __attribute__((address_space(1))) void*)g,
                                     (__attribute__((address_space(3))) void*)l, 16, 0, 0);
}

// ---------------------------------------------------------------------------
// Generic batched TN GEMM: C[i,j] = sum_k A[i,k]*B[j,k] (+bias[i])
// A: [I rows][K] row-stride lda (bf16), B: [J rows][K] row-stride ldb (bf16)
// C address = batch*c_bs + (i>>4)*ci_hi + (i&15)*ci_lo + (j>>4)*cj_hi + (j&15)*cj_lo
// Tile: 128x128, BK=64, 256 threads (4 waves 2x2), mfma 16x16x32 bf16.
// ---------------------------------------------------------------------------
template<int OUT_BF16, int HAS_BIAS>
__global__ __launch_bounds__(256, 2)
void gemm_tn(const ushort_t* __restrict__ A, const ushort_t* __restrict__ Bm,
             void* __restrict__ C, const float* __restrict__ bias,
             int K, int lda, int ldb,
             long a_bs, long b_bs, long c_bs, long bias_bs,
             long ci_hi, long ci_lo, long cj_hi, long cj_lo)
{
    __shared__ __align__(16) ushort_t As[128 * 64];
    __shared__ __align__(16) ushort_t Bs[128 * 64];

    const int t = threadIdx.x;
    const int lane = t & 63;
    const int w = t >> 6;
    const int wr = w >> 1, wc = w & 1;
    const int quad = lane >> 4, lr = lane & 15;
    const int i0 = blockIdx.y * 128;
    const int j0 = blockIdx.x * 128;
    const int batch = blockIdx.z;

    const ushort_t* Ab = A + (size_t)batch * a_bs;
    const ushort_t* Bb = Bm + (size_t)batch * b_bs;

    f32x4 acc[4][4];
#pragma unroll
    for (int a = 0; a < 4; ++a)
#pragma unroll
        for (int b = 0; b < 4; ++b)
            acc[a][b] = (f32x4){0.f, 0.f, 0.f, 0.f};

    for (int kt = 0; kt < K; kt += 64) {
#pragma unroll
        for (int c = 0; c < 4; ++c) {
            int idx = c * 256 + t;
            int row = idx >> 3, slot = idx & 7;
            int chunk = slot ^ (row & 7);
            const ushort_t* ga = Ab + (size_t)(i0 + row) * lda + kt + chunk * 8;
            const ushort_t* gb = Bb + (size_t)(j0 + row) * ldb + kt + chunk * 8;
            char* la = (char*)As + c * 4096 + w * 1024;
            char* lb = (char*)Bs + c * 4096 + w * 1024;
            async_copy16(ga, la);
            async_copy16(gb, lb);
        }
        __syncthreads();

#pragma unroll
        for (int ks = 0; ks < 2; ++ks) {
            bf16x8 af[4], bfr[4];
#pragma unroll
            for (int mt = 0; mt < 4; ++mt) {
                int row = wr * 64 + mt * 16 + lr;
                int chunk = ks * 4 + quad;
                int slot = chunk ^ (row & 7);
                af[mt] = *(const bf16x8*)((const char*)As + row * 128 + slot * 16);
            }
#pragma unroll
            for (int nt = 0; nt < 4; ++nt) {
                int col = wc * 64 + nt * 16 + lr;
                int chunk = ks * 4 + quad;
                int slot = chunk ^ (col & 7);
                bfr[nt] = *(const bf16x8*)((const char*)Bs + col * 128 + slot * 16);
            }
#pragma unroll
            for (int mt = 0; mt < 4; ++mt)
#pragma unroll
                for (int nt = 0; nt < 4; ++nt)
                    acc[mt][nt] = __builtin_amdgcn_mfma_f32_16x16x32_bf16(af[mt], bfr[nt], acc[mt][nt], 0, 0, 0);
        }
        __syncthreads();
    }

    long cbase = (long)batch * c_bs;
#pragma unroll
    for (int mt = 0; mt < 4; ++mt) {
#pragma unroll
        for (int nt = 0; nt < 4; ++nt) {
            int j = j0 + wc * 64 + nt * 16 + lr;
            long jpart = (long)(j >> 4) * cj_hi + (long)(j & 15) * cj_lo;
            f32x4 v = acc[mt][nt];
#pragma unroll
            for (int r = 0; r < 4; ++r) {
                int i = i0 + wr * 64 + mt * 16 + quad * 4 + r;
                float val = v[r];
                if (HAS_BIAS) val += bias[(size_t)batch * bias_bs + i];
                long addr = cbase + (long)(i >> 4) * ci_hi + (long)(i & 15) * ci_lo + jpart;
                if (OUT_BF16) ((ushort_t*)C)[addr] = f2bf(val);
                else          ((float*)C)[addr] = val;
            }
        }
    }
}

// ---------------------------------------------------------------------------
// Fused expert GEMM: eoT[b][e][n*16+p] = sum_d w[n][d][e]*slots[n][bp][d] + b_exp[n][e]
// Reads w fp32 directly (no pre-transpose pass): stages [64k][128e] fp32 tile
// via global_load_lds, transposes+casts in-LDS to the swizzled bf16 A-tile.
// grid (D/128, N). LDS = 16+16+32 = 64 KB -> 2 blocks/CU.
// ---------------------------------------------------------------------------
__global__ __launch_bounds__(256, 2)
void gemm_expert(const float* __restrict__ W, const ushort_t* __restrict__ S,
                 ushort_t* __restrict__ EO, const float* __restrict__ bias)
{
    __shared__ __align__(16) ushort_t As[128 * 64];
    __shared__ __align__(16) ushort_t Bs[128 * 64];
    __shared__ __align__(16) float    Wf[64 * 128];

    const int t = threadIdx.x;
    const int lane = t & 63;
    const int w = t >> 6;
    const int wr = w >> 1, wc = w & 1;
    const int quad = lane >> 4, lr = lane & 15;
    const int i0 = blockIdx.x * 128;      // e-tile
    const int n  = blockIdx.y;            // expert

    const float* Wn = W + (size_t)n * D_ * D_;
    const ushort_t* Sn = S + (size_t)n * 128 * D_;

    f32x4 acc[4][4];
#pragma unroll
    for (int a = 0; a < 4; ++a)
#pragma unroll
        for (int b = 0; b < 4; ++b)
            acc[a][b] = (f32x4){0.f, 0.f, 0.f, 0.f};

    const int e_tr = t & 127, half_tr = t >> 7;   // transpose work mapping

    for (int kt = 0; kt < D_; kt += 64) {
        // ---- stage slots (bf16, swizzled) ----
#pragma unroll
        for (int c = 0; c < 4; ++c) {
            int idx = c * 256 + t;
            int row = idx >> 3, slot = idx & 7;
            int chunk = slot ^ (row & 7);
            const ushort_t* gb = Sn + (size_t)row * D_ + kt + chunk * 8;
            char* lb = (char*)Bs + c * 4096 + w * 1024;
            async_copy16(gb, lb);
        }
        // ---- stage w fp32 [64k][128e], unpadded (global_load_lds constraint) ----
#pragma unroll
        for (int c = 0; c < 8; ++c) {
            int idx = c * 256 + t;
            int krow = idx >> 5, c16 = idx & 31;
            const float* gw = Wn + (size_t)(kt + krow) * D_ + i0 + c16 * 4;
            char* lw = (char*)Wf + c * 4096 + w * 1024;
            async_copy16(gw, lw);
        }
        __syncthreads();

        // ---- transpose + cast Wf -> As (bank: e%32, 2-way = free) ----
#pragma unroll
        for (int cc = 0; cc < 4; ++cc) {
            int chunk = half_tr * 4 + cc;
            float f[8];
#pragma unroll
            for (int j = 0; j < 8; ++j)
                f[j] = Wf[(chunk * 8 + j) * 128 + e_tr];
            union { ushort_t us[8]; bf16x8 v; } pk;
#pragma unroll
            for (int j = 0; j < 8; ++j) pk.us[j] = f2bf(f[j]);
            int slot = chunk ^ (e_tr & 7);
            *(bf16x8*)((char*)As + e_tr * 128 + slot * 16) = pk.v;
        }
        __syncthreads();

        // ---- MFMA ----
#pragma unroll
        for (int ks = 0; ks < 2; ++ks) {
            bf16x8 af[4], bfr[4];
#pragma unroll
            for (int mt = 0; mt < 4; ++mt) {
                int row = wr * 64 + mt * 16 + lr;
                int chunk = ks * 4 + quad;
                int slot = chunk ^ (row & 7);
                af[mt] = *(const bf16x8*)((const char*)As + row * 128 + slot * 16);
            }
#pragma unroll
            for (int nt = 0; nt < 4; ++nt) {
                int col = wc * 64 + nt * 16 + lr;
                int chunk = ks * 4 + quad;
                int slot = chunk ^ (col & 7);
                bfr[nt] = *(const bf16x8*)((const char*)Bs + col * 128 + slot * 16);
            }
#pragma unroll
            for (int mt = 0; mt < 4; ++mt)
#pragma unroll
                for (int nt = 0; nt < 4; ++nt)
                    acc[mt][nt] = __builtin_amdgcn_mfma_f32_16x16x32_bf16(af[mt], bfr[nt], acc[mt][nt], 0, 0, 0);
        }
        __syncthreads();
    }

    // ---- epilogue: eoT[b][e][n*16+p] + bias ----
#pragma unroll
    for (int mt = 0; mt < 4; ++mt) {
#pragma unroll
        for (int nt = 0; nt < 4; ++nt) {
            int j = wc * 64 + nt * 16 + lr;        // bp
            int bidx = j >> 4, p = j & 15;
            f32x4 v = acc[mt][nt];
#pragma unroll
            for (int r = 0; r < 4; ++r) {
                int i = i0 + wr * 64 + mt * 16 + quad * 4 + r;   // e
                float val = v[r] + bias[(size_t)n * D_ + i];
                EO[(size_t)bidx * ((size_t)D_ * NP_) + (size_t)i * NP_ + n * 16 + p] = f2bf(val);
            }
        }
    }
}

// ---------------------------------------------------------------------------
// prep_x: read x fp32 [b][M][D] once; write xbf [bm][D] bf16 (straight cast)
// and xT [b][D][M] bf16 (transposed). grid (D/64, M/64, B). pad-65 tile:
// write banks (row+c)%32 2-way, transposed read banks (2a+rr)%32 2-way.
// ---------------------------------------------------------------------------
__global__ __launch_bounds__(256)
void prep_x(const float* __restrict__ x, ushort_t* __restrict__ xbf,
            ushort_t* __restrict__ xT)
{
    __shared__ float tile[64][65];
    int t = threadIdx.x;
    int b = blockIdx.z;
    int d0 = blockIdx.x * 64, m0 = blockIdx.y * 64;
    const float* ib = x + (size_t)b * M_ * D_;

#pragma unroll
    for (int it = 0; it < 4; ++it) {
        int row = it * 16 + (t >> 4);      // m local
        int c4 = (t & 15) * 4;             // d local
        float4 f = *(const float4*)(ib + (size_t)(m0 + row) * D_ + d0 + c4);
        union { ushort_t us[4]; uint2 v; } pk;
        pk.us[0] = f2bf(f.x); pk.us[1] = f2bf(f.y);
        pk.us[2] = f2bf(f.z); pk.us[3] = f2bf(f.w);
        *(uint2*)(xbf + ((size_t)b * M_ + m0 + row) * D_ + d0 + c4) = pk.v;
        tile[row][c4]     = f.x;
        tile[row][c4 + 1] = f.y;
        tile[row][c4 + 2] = f.z;
        tile[row][c4 + 3] = f.w;
    }
    __syncthreads();
#pragma unroll
    for (int it = 0; it < 8; ++it) {
        int rr = it * 8 + (t >> 5);        // d local
        int cc = (t & 31) * 2;             // m local
        ushort2 pk;
        pk.x = f2bf(tile[cc][rr]);
        pk.y = f2bf(tile[cc + 1][rr]);
        *(ushort2*)(xT + (size_t)b * D_ * M_ + (size_t)(d0 + rr) * M_ + m0 + cc) = pk;
    }
}

// ---------------------------------------------------------------------------
// Tiled transpose + cast (phi only): in fp32 [R][C] -> out bf16 [C][R]
// ---------------------------------------------------------------------------
__global__ __launch_bounds__(256)
void transpose_cast(const float* __restrict__ in, ushort_t* __restrict__ out,
                    int ldi, int ldo, long in_bs, long out_bs)
{
    __shared__ float tile[64][65];
    int t = threadIdx.x;
    const float* ib = in + (size_t)blockIdx.z * in_bs;
    ushort_t* ob = out + (size_t)blockIdx.z * out_bs;
    int c0 = blockIdx.x * 64, r0 = blockIdx.y * 64;
#pragma unroll
    for (int it = 0; it < 16; ++it) {
        int r = it * 4 + (t >> 6);
        int c = t & 63;
        tile[r][c] = ib[(size_t)(r0 + r) * ldi + c0 + c];
    }
    __syncthreads();
#pragma unroll
    for (int it = 0; it < 8; ++it) {
        int rr = it * 8 + (t >> 5);
        int cc = (t & 31) * 2;
        ushort2 pk;
        pk.x = f2bf(tile[cc][rr]);
        pk.y = f2bf(tile[cc + 1][rr]);
        *(ushort2*)(ob + (size_t)(c0 + rr) * ldo + r0 + cc) = pk;
    }
}

// ---------------------------------------------------------------------------
// Dispatch softmax over b (8 vals) of L[b][m][np] bf16 -> dT[b][np][m] bf16
// Tile 32(m) x 64(np); grid (NP/64, M/32).
// ---------------------------------------------------------------------------
__global__ __launch_bounds__(256)
void softmax_b(const ushort_t* __restrict__ L, ushort_t* __restrict__ dT)
{
    int t = threadIdx.x;
    int n0 = blockIdx.x * 64, m0 = blockIdx.y * 32;
    int ncol = t & 63, mb = t >> 6;

    float vals[8][8];
#pragma unroll
    for (int b = 0; b < 8; ++b)
#pragma unroll
        for (int it = 0; it < 8; ++it) {
            int m = m0 + it * 4 + mb;
            vals[b][it] = bf2f(L[(size_t)b * (M_ * (size_t)NP_) + (size_t)m * NP_ + n0 + ncol]);
        }

    float inv[8];
#pragma unroll
    for (int it = 0; it < 8; ++it) {
        float mx = vals[0][it];
#pragma unroll
        for (int b = 1; b < 8; ++b) mx = fmaxf(mx, vals[b][it]);
        float s = 0.f;
#pragma unroll
        for (int b = 0; b < 8; ++b) { vals[b][it] = __expf(vals[b][it] - mx); s += vals[b][it]; }
        inv[it] = 1.f / s;
    }

    __shared__ float tile[64][33];
#pragma unroll
    for (int b = 0; b < 8; ++b) {
        __syncthreads();
#pragma unroll
        for (int it = 0; it < 8; ++it)
            tile[ncol][it * 4 + mb] = vals[b][it] * inv[it];
        __syncthreads();
#pragma unroll
        for (int it2 = 0; it2 < 4; ++it2) {
            int rr = it2 * 16 + (t >> 4);
            int cc = (t & 15) * 2;
            ushort2 pk;
            pk.x = f2bf(tile[rr][cc]);
            pk.y = f2bf(tile[rr][cc + 1]);
            *(ushort2*)(dT + (size_t)b * (NP_ * (size_t)M_) + (size_t)(n0 + rr) * M_ + m0 + cc) = pk;
        }
    }
}

// ---------------------------------------------------------------------------
// Combine softmax over 2048 slots per (b,m) row of bf16 L -> cmb bf16.
// ---------------------------------------------------------------------------
__global__ __launch_bounds__(256)
void softmax_np(const ushort_t* __restrict__ L, ushort_t* __restrict__ Cb)
{
    int row = blockIdx.x;
    const ushort_t* Lr = L + (size_t)row * NP_;
    int t = threadIdx.x;
    int w = t >> 6, lane = t & 63;

    union { int4 v4; ushort_t us[8]; } ld;
    ld.v4 = *(const int4*)(Lr + t * 8);
    float v[8];
#pragma unroll
    for (int j = 0; j < 8; ++j) v[j] = bf2f(ld.us[j]);

    float mx = v[0];
#pragma unroll
    for (int j = 1; j < 8; ++j) mx = fmaxf(mx, v[j]);
#pragma unroll
    for (int off = 32; off > 0; off >>= 1) mx = fmaxf(mx, __shfl_xor(mx, off));

    __shared__ float red[8];
    if (lane == 0) red[w] = mx;
    __syncthreads();
    mx = fmaxf(fmaxf(red[0], red[1]), fmaxf(red[2], red[3]));

    float s = 0.f;
#pragma unroll
    for (int j = 0; j < 8; ++j) { v[j] = __expf(v[j] - mx); s += v[j]; }
#pragma unroll
    for (int off = 32; off > 0; off >>= 1) s += __shfl_xor(s, off);
    if (lane == 0) red[4 + w] = s;
    __syncthreads();
    s = red[4] + red[5] + red[6] + red[7];
    float is = 1.f / s;

    union { ushort_t us[8]; int4 v4; } pk;
#pragma unroll
    for (int j = 0; j < 8; ++j) pk.us[j] = f2bf(v[j] * is);
    *(int4*)(Cb + (size_t)row * NP_ + t * 8) = pk.v4;
}

// ---------------------------------------------------------------------------
// Host launch
// ---------------------------------------------------------------------------
extern "C" void kernel_launch(void* const* d_in, const int* in_sizes, int n_in,
                              void* d_out, int out_size, void* d_ws, size_t ws_size,
                              hipStream_t stream)
{
    (void)in_sizes; (void)n_in; (void)out_size; (void)ws_size;
    const float* x     = (const float*)d_in[0];   // [B][M][D]
    const float* phi   = (const float*)d_in[1];   // [D][N*P]
    const float* w_exp = (const float*)d_in[2];   // [N][D][D]
    const float* b_exp = (const float*)d_in[3];   // [N][D]
    float* out = (float*)d_out;                   // [B][M][D]
    char* ws = (char*)d_ws;

    // workspace layout (bytes), total ~340 MB
    ushort_t* xbf   = (ushort_t*)(ws + 0);          // 33.5 MB  [BM][D]
    ushort_t* xT    = (ushort_t*)(ws + 33554432);   // 33.5 MB  [b][D][M]
    ushort_t* phiT  = (ushort_t*)(ws + 67108864);   // 4 MB     [NP][D]
    ushort_t* L     = (ushort_t*)(ws + 71303168);   // 67 MB    [BM][NP] bf16
    ushort_t* dT    = (ushort_t*)(ws + 138412032);  // 67 MB    [b][NP][M]
    ushort_t* cmb   = (ushort_t*)(ws + 205520896);  // 67 MB    [b][M][NP]
    ushort_t* slots = (ushort_t*)(ws + 272629760);  // 33.5 MB  [n][b][p][d]
    ushort_t* eoT   = (ushort_t*)(ws + 306184192);  // 33.5 MB  [b][e][np]

    // 1. x -> xbf (cast) + xT (transpose), single read of x
    prep_x<<<dim3(D_ / 64, M_ / 64, B_), 256, 0, stream>>>(x, xbf, xT);
    // 2. phi [D][NP] -> phiT [NP][D]
    transpose_cast<<<dim3(NP_ / 64, D_ / 64, 1), 256, 0, stream>>>(phi, phiT, NP_, D_, 0, 0);
    // 3. Stage A: L[bm][np] = sum_d xbf[bm][d]*phiT[np][d]  (bf16 out)
    gemm_tn<1, 0><<<dim3(NP_ / 128, BM_ / 128, 1), 256, 0, stream>>>(
        xbf, phiT, L, nullptr, D_, D_, D_,
        0, 0, 0, 0,
        16L * NP_, NP_, 16, 1);
    // 4. dispatch softmax (over b) -> dT [b][np][m]
    softmax_b<<<dim3(NP_ / 64, M_ / 32), 256, 0, stream>>>(L, dT);
    // 5. combine softmax (over np) -> cmb [b][m][np]
    softmax_np<<<dim3(B_ * M_), 256, 0, stream>>>(L, cmb);
    // 6. Stage C: slots[n][b][p][d] = sum_m dT[b][np][m]*xT[b][d][m]
    gemm_tn<1, 0><<<dim3(D_ / 128, NP_ / 128, B_), 256, 0, stream>>>(
        dT, xT, slots, nullptr, M_, M_, M_,
        (long)NP_ * M_, (long)D_ * M_, (long)P_ * D_, 0,
        (long)B_ * P_ * D_, D_, 16, 1);
    // 7. Stage D fused: eoT[b][e][np] = sum_d w[n][d][e]*slots[n][bp][d] + b_exp
    gemm_expert<<<dim3(D_ / 128, N_), 256, 0, stream>>>(w_exp, slots, eoT, b_exp);
    // 8. Stage E: out[b][m][d] = sum_np cmb[b][m][np]*eoT[b][d][np]  (fp32 out)
    gemm_tn<0, 0><<<dim3(D_ / 128, M_ / 128, B_), 256, 0, stream>>>(
        cmb, eoT, out, nullptr, NP_, NP_, NP_,
        (long)M_ * NP_, (long)D_ * NP_, (long)M_ * D_, 0,
        16L * D_, D_, 16, 1);
}